// Round 9
// baseline (226.231 us; speedup 1.0000x reference)
//
#include <hip/hip_runtime.h>
#include <hip/hip_bf16.h>
#include <cstddef>
#include <cstdint>

#define DIM 128
#define SCAN_CHUNK 2048   // 256 threads x 8 elems

typedef __attribute__((ext_vector_type(8))) short short8v;  // 8 bf16 (4 VGPR)
typedef __attribute__((ext_vector_type(4))) float f32x4;    // MFMA acc

__device__ __forceinline__ float leaky(float v) {
    return v > 0.0f ? v : 0.01f * v;
}

__device__ __forceinline__ unsigned short f2bf(float f) {
    unsigned u = __builtin_bit_cast(unsigned, f);
    u += 0x7FFF + ((u >> 16) & 1);      // round-to-nearest-even
    return (unsigned short)(u >> 16);
}

// pack two f32 -> one u32 of 2 bf16 (lo = a, hi = b), single HW instr
__device__ __forceinline__ unsigned cvt_pk_bf16(float a, float b) {
    unsigned r;
    asm("v_cvt_pk_bf16_f32 %0, %1, %2" : "=v"(r) : "v"(a), "v"(b));
    return r;
}

__device__ __forceinline__ float bf2f_hi(unsigned p) {
    return __builtin_bit_cast(float, p & 0xFFFF0000u);
}
__device__ __forceinline__ float bf2f_lo(unsigned p) {
    return __builtin_bit_cast(float, p << 16);
}

// async global->LDS, 16 B per lane; LDS dest = wave-uniform base + lane*16
__device__ __forceinline__ void gload_lds16(const float* g, float* lds) {
    __builtin_amdgcn_global_load_lds(
        (const __attribute__((address_space(1))) unsigned int*)g,
        (__attribute__((address_space(3))) unsigned int*)lds, 16, 0, 0);
}

// ---------------------------------------------------------------------------
// init: zero cnt[]  +  W transpose/convert
// ---------------------------------------------------------------------------
__global__ __launch_bounds__(256)
void init_kernel(const float* __restrict__ Wg, const float* __restrict__ Wf,
                 unsigned short* __restrict__ WgT, unsigned short* __restrict__ WfT,
                 int* __restrict__ cnt, int N) {
    int t = blockIdx.x * 256 + threadIdx.x;
    if (t < N) cnt[t] = 0;
    if (t < 128 * 128) {
        int col = t >> 7, k = t & 127;
        WgT[col * 128 + k] = f2bf(Wg[k * 128 + col]);
        WfT[col * 128 + k] = f2bf(Wf[k * 128 + col]);
    }
}

// ---------------------------------------------------------------------------
// histogram of in-degree counts
// ---------------------------------------------------------------------------
__global__ __launch_bounds__(256)
void hist_kernel(const int* __restrict__ col, int* __restrict__ cnt, int E) {
    int e = blockIdx.x * blockDim.x + threadIdx.x;
    if (e < E) atomicAdd(&cnt[col[e]], 1);
}

// ---------------------------------------------------------------------------
// Scan pass 1: per-chunk sums of cnt
// ---------------------------------------------------------------------------
__global__ __launch_bounds__(256)
void scan_block_sums(const int* __restrict__ cnt, int* __restrict__ bsum, int N) {
    __shared__ int sdata[4];
    int base = blockIdx.x * SCAN_CHUNK;
    int s = 0;
    for (int k = threadIdx.x; k < SCAN_CHUNK; k += 256) {
        int idx = base + k;
        s += (idx < N) ? cnt[idx] : 0;
    }
#pragma unroll
    for (int m = 1; m < 64; m <<= 1) s += __shfl_xor(s, m, 64);
    if ((threadIdx.x & 63) == 0) sdata[threadIdx.x >> 6] = s;
    __syncthreads();
    if (threadIdx.x == 0)
        bsum[blockIdx.x] = sdata[0] + sdata[1] + sdata[2] + sdata[3];
}

// ---------------------------------------------------------------------------
// Scan pass 2: exclusive scan of chunk sums (nb <= 128)
// ---------------------------------------------------------------------------
__global__ __launch_bounds__(128)
void scan_bsum_kernel(int* __restrict__ bsum, int nb) {
    __shared__ int wtot[2];
    int t = threadIdx.x;
    int lane = t & 63;
    int orig = (t < nb) ? bsum[t] : 0;
    int v = orig;
#pragma unroll
    for (int m = 1; m < 64; m <<= 1) {
        int u = __shfl_up(v, m, 64);
        if (lane >= m) v += u;
    }
    if (lane == 63) wtot[t >> 6] = v;
    __syncthreads();
    if (t >= 64) v += wtot[0];
    if (t < nb) bsum[t] = v - orig;   // exclusive
}

// ---------------------------------------------------------------------------
// Scan pass 3: exclusive scan -> off[0..N], cursor copy into cnt[]
// ---------------------------------------------------------------------------
__global__ __launch_bounds__(256)
void scan_write_kernel(int* __restrict__ cnt, const int* __restrict__ bsum,
                       int* __restrict__ off, int N) {
    __shared__ int wsum[4];
    int t = threadIdx.x;
    int base = blockIdx.x * SCAN_CHUNK + t * 8;
    int vals[8];
    int local = 0;
#pragma unroll
    for (int k = 0; k < 8; ++k) {
        int idx = base + k;
        int c = (idx < N) ? cnt[idx] : 0;
        vals[k] = local;
        local += c;
    }
    int tsum = local;
    int lane = t & 63;
    int v = tsum;
#pragma unroll
    for (int m = 1; m < 64; m <<= 1) {
        int u = __shfl_up(v, m, 64);
        if (lane >= m) v += u;
    }
    if (lane == 63) wsum[t >> 6] = v;
    __syncthreads();
    int woff = 0;
    for (int i = 0; i < (t >> 6); ++i) woff += wsum[i];
    int texcl = (v - tsum) + woff + bsum[blockIdx.x];
#pragma unroll
    for (int k = 0; k < 8; ++k) {
        int idx = base + k;
        int o = texcl + vals[k];
        if (idx <= N) off[idx] = o;
    }
    __syncthreads();
#pragma unroll
    for (int k = 0; k < 8; ++k) {
        int idx = base + k;
        int o = texcl + vals[k];
        if (idx < N) cnt[idx] = o;
    }
}

// ---------------------------------------------------------------------------
// Reorder edges into CSR-by-target, packed (row, weight) int2
// ---------------------------------------------------------------------------
__global__ __launch_bounds__(256)
void reorder_kernel(const int* __restrict__ row, const int* __restrict__ col,
                    const float* __restrict__ w, int* __restrict__ cursor,
                    int2* __restrict__ edgeRW, int E) {
    int e = blockIdx.x * blockDim.x + threadIdx.x;
    if (e < E) {
        int c = col[e];
        int pos = atomicAdd(&cursor[c], 1);
        edgeRW[pos] = make_int2(row[e], __builtin_bit_cast(int, w[e]));
    }
}

// ---------------------------------------------------------------------------
// dinv from CSR: dinv[i] = rsqrt(1 + sum_j w_j)
// ---------------------------------------------------------------------------
__global__ __launch_bounds__(256)
void csr_dinv_kernel(const int* __restrict__ off, const int2* __restrict__ edgeRW,
                     float* __restrict__ dinv, int N) {
    int i = blockIdx.x * 256 + threadIdx.x;
    if (i >= N) return;
    int s = off[i], e = off[i + 1];
    float acc = 1.0f;
    for (int j = s; j < e; ++j)
        acc += __builtin_bit_cast(float, edgeRW[j].y);
    dinv[i] = rsqrtf(acc);
}

// ---------------------------------------------------------------------------
// PERSISTENT double-buffered MFMA dual GEMM.
// 512 blocks x 512 threads grid-stride over 64-row tiles (ntiles = ceil(N/64)).
// LDS: 2 x 32KB f32 buffers. Loop:
//   __syncthreads()  (drains stage issued LAST iteration -> buf[cur] ready)
//   stage(tile+nb -> buf[cur^1])  (async DMA, fills under compute)
//   compute+store(tile from buf[cur])
// W fragments (16 KB/wave) hoisted into registers ONCE before the loop ->
// zero in-loop global loads besides the DMA stage.
// Wave wv: rows half h=wv>>2 (32 rows), col quarter q=wv&3 (32 cols).
// Operands swapped: mfma(W_frag, x_frag) -> lane owns (row, 4 consecutive
// cols) -> 8 B packed bf16 stores.
//   hsb  = bf16(dinv*h) ; accb = bf16( leaky(f + bf) + bg + dinv*(dinv*h) )
// ---------------------------------------------------------------------------
__global__ __launch_bounds__(512, 4)
void gemm_mfma_kernel(const float* __restrict__ x_src, const float* __restrict__ x_tar,
                      int n_src, int n_total, int ntiles,
                      const unsigned short* __restrict__ WgT,
                      const unsigned short* __restrict__ WfT,
                      const float* __restrict__ bg, const float* __restrict__ bf,
                      const float* __restrict__ dinv,
                      unsigned short* __restrict__ hsb,
                      unsigned short* __restrict__ accb)
{
    __shared__ float Ash[2][64 * 128];   // 2 x 32 KB f32, 16B-chunk swizzled

    const int t    = threadIdx.x;
    const int lane = t & 63;
    const int wv   = t >> 6;          // 0..7
    const int h    = wv >> 2;         // row half (0..1): 32 rows
    const int q    = wv & 3;          // col quarter (0..3): 32 cols
    const int lr   = lane & 15;
    const int lk   = lane >> 4;
    const int nb   = gridDim.x;

    // ---- hoist W fragments into registers (once) ----
    short8v wg[4][2], wf[4][2];
#pragma unroll
    for (int ks = 0; ks < 4; ++ks)
#pragma unroll
        for (int nf = 0; nf < 2; ++nf) {
            int col = q * 32 + nf * 16 + lr;
            const size_t bo = (size_t)col * 128 + ks * 32 + lk * 8;
            wg[ks][nf] = *(const short8v*)(WgT + bo);
            wf[ks][nf] = *(const short8v*)(WfT + bo);
        }

    // stage: 2048 x 16B chunks / 512 threads = 4 DMA per thread.
    // LDS dest linear (chunk id), global source chunk XOR-swizzled.
    auto stage = [&](int tl, int buf) {
#pragma unroll
        for (int s = 0; s < 4; ++s) {
            int id  = s * 512 + t;       // dest chunk id
            int row = id >> 5;           // 0..63
            int cs  = id & 31;
            int c   = cs ^ (row & 15);   // source chunk within row
            int rg  = tl * 64 + row;
            if (rg >= n_total) rg = n_total - 1;
            const float* xr = (rg < n_src) ? x_src + (size_t)rg * DIM
                                           : x_tar + (size_t)(rg - n_src) * DIM;
            gload_lds16(xr + c * 4, &Ash[buf][(size_t)(s * 512 + wv * 64) * 4]);
        }
    };

    int tile = blockIdx.x;
    if (tile < ntiles) stage(tile, 0);
    int cur = 0;

    for (; tile < ntiles; tile += nb) {
        __syncthreads();                 // vmcnt(0): buf[cur] filled, prev stores drained
        if (tile + nb < ntiles) stage(tile + nb, cur ^ 1);

        f32x4 accg[2][2], accf[2][2];
#pragma unroll
        for (int i = 0; i < 2; ++i)
#pragma unroll
            for (int j = 0; j < 2; ++j) {
                accg[i][j] = (f32x4)0.0f;
                accf[i][j] = (f32x4)0.0f;
            }

#pragma unroll
        for (int ks = 0; ks < 4; ++ks) {
            short8v xf[2];               // x-row fragments (bf16)
#pragma unroll
            for (int mf = 0; mf < 2; ++mf) {
                int row = h * 32 + mf * 16 + lr;
                int c0  = ks * 8 + lk * 2;
                float4 q0 = *(const float4*)&Ash[cur][(size_t)(row * 32 + ( c0      ^ (row & 15))) * 4];
                float4 q1 = *(const float4*)&Ash[cur][(size_t)(row * 32 + ((c0 + 1) ^ (row & 15))) * 4];
                union { short8v v; unsigned u[4]; } cv;
                cv.u[0] = cvt_pk_bf16(q0.x, q0.y);
                cv.u[1] = cvt_pk_bf16(q0.z, q0.w);
                cv.u[2] = cvt_pk_bf16(q1.x, q1.y);
                cv.u[3] = cvt_pk_bf16(q1.z, q1.w);
                xf[mf] = cv.v;
            }
#pragma unroll
            for (int nf = 0; nf < 2; ++nf)
#pragma unroll
                for (int mf = 0; mf < 2; ++mf) {
                    accg[mf][nf] = __builtin_amdgcn_mfma_f32_16x16x32_bf16(wg[ks][nf], xf[mf], accg[mf][nf], 0, 0, 0);
                    accf[mf][nf] = __builtin_amdgcn_mfma_f32_16x16x32_bf16(wf[ks][nf], xf[mf], accf[mf][nf], 0, 0, 0);
                }
        }

        // ---- epilogue: lane owns (row, cols c0..c0+3), 8 B packed stores ----
#pragma unroll
        for (int mf = 0; mf < 2; ++mf) {
            int r = tile * 64 + h * 32 + mf * 16 + lr;
            const bool valid = (r < n_total);
            int rc = valid ? r : (n_total - 1);
            float dv = dinv[rc];
#pragma unroll
            for (int nf = 0; nf < 2; ++nf) {
                int c0 = q * 32 + nf * 16 + lk * 4;
                float4 bgv = *(const float4*)(bg + c0);
                float4 bfv = *(const float4*)(bf + c0);

                float hs0 = dv * accg[mf][nf][0];
                float hs1 = dv * accg[mf][nf][1];
                float hs2 = dv * accg[mf][nf][2];
                float hs3 = dv * accg[mf][nf][3];

                float o0 = leaky(accf[mf][nf][0] + bfv.x) + bgv.x + dv * hs0;
                float o1 = leaky(accf[mf][nf][1] + bfv.y) + bgv.y + dv * hs1;
                float o2 = leaky(accf[mf][nf][2] + bfv.z) + bgv.z + dv * hs2;
                float o3 = leaky(accf[mf][nf][3] + bfv.w) + bgv.w + dv * hs3;

                uint2 hp, op;
                hp.x = cvt_pk_bf16(hs0, hs1);
                hp.y = cvt_pk_bf16(hs2, hs3);
                op.x = cvt_pk_bf16(o0, o1);
                op.y = cvt_pk_bf16(o2, o3);

                if (valid) {
                    *(uint2*)(hsb  + (size_t)r * DIM + c0) = hp;
                    *(uint2*)(accb + (size_t)r * DIM + c0) = op;
                }
            }
        }
        cur ^= 1;
    }
}

// ---------------------------------------------------------------------------
// Gather + fused layernorm + leaky_relu.
// 4 nodes per wave: 16 lanes x 8 dims each (16B uint4 gathers), pipelined.
//   out[i] = norm( accb[i] + dinv[i] * sum_{e->i} w_e * hsb[row_e] )
// ---------------------------------------------------------------------------
__global__ __launch_bounds__(256)
void gather_norm_kernel(const int* __restrict__ off, const int2* __restrict__ edgeRW,
                        const float* __restrict__ dinv,
                        const unsigned short* __restrict__ hsb,
                        const unsigned short* __restrict__ accb,
                        float* __restrict__ out, int n)
{
    const int wid  = threadIdx.x >> 6;
    const int lane = threadIdx.x & 63;
    const int sub  = lane >> 4;       // node within wave (0..3)
    const int sl   = lane & 15;       // lane within node, owns dims sl*8..+7
    int i = (blockIdx.x * 4 + wid) * 4 + sub;
    if (i >= n) i = n - 1;

    const int start = off[i];
    const int degc  = off[i + 1] - start;

    int md = degc;
    md = max(md, __shfl_xor(md, 16, 64));
    md = max(md, __shfl_xor(md, 32, 64));

    float s[8];
#pragma unroll
    for (int k = 0; k < 8; ++k) s[k] = 0.0f;

    const unsigned short* gbase = hsb + (size_t)sl * 8;

    int   r0 = 0, r1 = 0;
    float w0 = 0.0f, w1 = 0.0f;
    if (0 < degc) { int2 m = edgeRW[start];     r0 = m.x; w0 = __builtin_bit_cast(float, m.y); }
    if (1 < degc) { int2 m = edgeRW[start + 1]; r1 = m.x; w1 = __builtin_bit_cast(float, m.y); }
    uint4 p0 = *(const uint4*)(gbase + (size_t)r0 * DIM);

    for (int t = 0; t < md; ++t) {
        uint4 p1 = p0;
        if (t + 1 < md)
            p1 = *(const uint4*)(gbase + (size_t)r1 * DIM);
        int r2 = 0; float w2 = 0.0f;
        if (t + 2 < md) {
            if (t + 2 < degc) {
                int2 m = edgeRW[start + t + 2];
                r2 = m.x; w2 = __builtin_bit_cast(float, m.y);
            }
        }
        s[0] += w0 * bf2f_lo(p0.x); s[1] += w0 * bf2f_hi(p0.x);
        s[2] += w0 * bf2f_lo(p0.y); s[3] += w0 * bf2f_hi(p0.y);
        s[4] += w0 * bf2f_lo(p0.z); s[5] += w0 * bf2f_hi(p0.z);
        s[6] += w0 * bf2f_lo(p0.w); s[7] += w0 * bf2f_hi(p0.w);
        p0 = p1;
        r0 = r1; w0 = w1;
        r1 = r2; w1 = w2;
    }

    const float dv = dinv[i];
    uint4 av = *(const uint4*)(accb + (size_t)i * DIM + sl * 8);
    float v[8];
    v[0] = bf2f_lo(av.x) + dv * s[0]; v[1] = bf2f_hi(av.x) + dv * s[1];
    v[2] = bf2f_lo(av.y) + dv * s[2]; v[3] = bf2f_hi(av.y) + dv * s[3];
    v[4] = bf2f_lo(av.z) + dv * s[4]; v[5] = bf2f_hi(av.z) + dv * s[5];
    v[6] = bf2f_lo(av.w) + dv * s[6]; v[7] = bf2f_hi(av.w) + dv * s[7];

    float sum = 0.0f;
#pragma unroll
    for (int k = 0; k < 8; ++k) sum += v[k];
#pragma unroll
    for (int m = 1; m < 16; m <<= 1) sum += __shfl_xor(sum, m, 64);
    const float mean = sum * (1.0f / 128.0f);

    float sq = 0.0f;
#pragma unroll
    for (int k = 0; k < 8; ++k) {
        v[k] -= mean;
        sq += v[k] * v[k];
    }
#pragma unroll
    for (int m = 1; m < 16; m <<= 1) sq += __shfl_xor(sq, m, 64);
    const float rstd = rsqrtf(sq * (1.0f / 128.0f) + 1e-6f);

    float4 o1, o2;
    o1.x = leaky(v[0] * rstd); o1.y = leaky(v[1] * rstd);
    o1.z = leaky(v[2] * rstd); o1.w = leaky(v[3] * rstd);
    o2.x = leaky(v[4] * rstd); o2.y = leaky(v[5] * rstd);
    o2.z = leaky(v[6] * rstd); o2.w = leaky(v[7] * rstd);
    float* op = out + (size_t)i * DIM + sl * 8;
    *(float4*)op       = o1;
    *(float4*)(op + 4) = o2;
}

// ---------------------------------------------------------------------------
extern "C" void kernel_launch(void* const* d_in, const int* in_sizes, int n_in,
                              void* d_out, int out_size, void* d_ws, size_t ws_size,
                              hipStream_t stream)
{
    const float* x_src = (const float*)d_in[0];
    const float* x_tar = (const float*)d_in[1];
    const int*   ei    = (const int*)d_in[2];
    const float* ew    = (const float*)d_in[3];
    const float* Wg    = (const float*)d_in[4];
    const float* bg    = (const float*)d_in[5];
    const float* Wf    = (const float*)d_in[6];
    const float* bf    = (const float*)d_in[7];

    const int n_src = in_sizes[0] / DIM;
    const int n_tar = in_sizes[1] / DIM;
    const int N     = n_src + n_tar;
    const int E     = in_sizes[3];

    const int* rowp = ei;       // edge_index[0] = message source
    const int* colp = ei + E;   // edge_index[1] = message target

    // ---- workspace layout ----
    char* p = (char*)d_ws;
    float* dinv = (float*)p;  p += (size_t)N * 4;
    int*   cnt  = (int*)p;    p += (size_t)N * 4;
    int*   off  = (int*)p;    p += (size_t)(N + 1) * 4;
    int*   bsum = (int*)p;    p += 160 * 4;
    p = (char*)(((uintptr_t)p + 15) & ~(uintptr_t)15);
    int2*  edgeRW = (int2*)p; p += (size_t)E * 8;
    unsigned short* hsb  = (unsigned short*)p; p += (size_t)N * DIM * 2;
    unsigned short* accb = (unsigned short*)p; p += (size_t)N * DIM * 2;
    unsigned short* WgT  = (unsigned short*)p; p += 128 * 128 * 2;
    unsigned short* WfT  = (unsigned short*)p;

    const int NB = (N + 1 + SCAN_CHUNK - 1) / SCAN_CHUNK;

    init_kernel<<<(N + 255) / 256, 256, 0, stream>>>(Wg, Wf, WgT, WfT, cnt, N);

    hist_kernel<<<(E + 255) / 256, 256, 0, stream>>>(colp, cnt, E);

    scan_block_sums<<<NB, 256, 0, stream>>>(cnt, bsum, N);
    scan_bsum_kernel<<<1, 128, 0, stream>>>(bsum, NB);
    scan_write_kernel<<<NB, 256, 0, stream>>>(cnt, bsum, off, N);

    reorder_kernel<<<(E + 255) / 256, 256, 0, stream>>>(rowp, colp, ew, cnt,
                                                        edgeRW, E);

    csr_dinv_kernel<<<(N + 255) / 256, 256, 0, stream>>>(off, edgeRW, dinv, N);

    const int ntiles = (N + 63) / 64;
    gemm_mfma_kernel<<<512, 512, 0, stream>>>(
        x_src, x_tar, n_src, N, ntiles, WgT, WfT, bg, bf, dinv, hsb, accb);

    gather_norm_kernel<<<(N + 15) / 16, 256, 0, stream>>>(
        off, edgeRW, dinv, hsb, accb, (float*)d_out, N);
}

// Round 10
// 205.576 us; speedup vs baseline: 1.1005x; 1.1005x over previous
//
#include <hip/hip_runtime.h>
#include <hip/hip_bf16.h>
#include <cstddef>
#include <cstdint>

#define DIM 128
#define SCAN_CHUNK 2048   // 256 threads x 8 elems

typedef __attribute__((ext_vector_type(8))) short short8v;  // 8 bf16 (4 VGPR)
typedef __attribute__((ext_vector_type(4))) float f32x4;    // MFMA acc

__device__ __forceinline__ float leaky(float v) {
    return v > 0.0f ? v : 0.01f * v;
}

__device__ __forceinline__ unsigned short f2bf(float f) {
    unsigned u = __builtin_bit_cast(unsigned, f);
    u += 0x7FFF + ((u >> 16) & 1);      // round-to-nearest-even
    return (unsigned short)(u >> 16);
}

// pack two f32 -> one u32 of 2 bf16 (lo = a, hi = b), single HW instr
__device__ __forceinline__ unsigned cvt_pk_bf16(float a, float b) {
    unsigned r;
    asm("v_cvt_pk_bf16_f32 %0, %1, %2" : "=v"(r) : "v"(a), "v"(b));
    return r;
}

__device__ __forceinline__ float bf2f_hi(unsigned p) {
    return __builtin_bit_cast(float, p & 0xFFFF0000u);
}
__device__ __forceinline__ float bf2f_lo(unsigned p) {
    return __builtin_bit_cast(float, p << 16);
}

// async global->LDS, 16 B per lane; LDS dest = wave-uniform base + lane*16
__device__ __forceinline__ void gload_lds16(const float* g, float* lds) {
    __builtin_amdgcn_global_load_lds(
        (const __attribute__((address_space(1))) unsigned int*)g,
        (__attribute__((address_space(3))) unsigned int*)lds, 16, 0, 0);
}

// ---------------------------------------------------------------------------
// init: zero cnt[]  +  W transpose/convert
// ---------------------------------------------------------------------------
__global__ __launch_bounds__(256)
void init_kernel(const float* __restrict__ Wg, const float* __restrict__ Wf,
                 unsigned short* __restrict__ WgT, unsigned short* __restrict__ WfT,
                 int* __restrict__ cnt, int N) {
    int t = blockIdx.x * 256 + threadIdx.x;
    if (t < N) cnt[t] = 0;
    if (t < 128 * 128) {
        int col = t >> 7, k = t & 127;
        WgT[col * 128 + k] = f2bf(Wg[k * 128 + col]);
        WfT[col * 128 + k] = f2bf(Wf[k * 128 + col]);
    }
}

// ---------------------------------------------------------------------------
// histogram of in-degree counts
// ---------------------------------------------------------------------------
__global__ __launch_bounds__(256)
void hist_kernel(const int* __restrict__ col, int* __restrict__ cnt, int E) {
    int e = blockIdx.x * blockDim.x + threadIdx.x;
    if (e < E) atomicAdd(&cnt[col[e]], 1);
}

// ---------------------------------------------------------------------------
// Scan pass 1: per-chunk sums of cnt
// ---------------------------------------------------------------------------
__global__ __launch_bounds__(256)
void scan_block_sums(const int* __restrict__ cnt, int* __restrict__ bsum, int N) {
    __shared__ int sdata[4];
    int base = blockIdx.x * SCAN_CHUNK;
    int s = 0;
    for (int k = threadIdx.x; k < SCAN_CHUNK; k += 256) {
        int idx = base + k;
        s += (idx < N) ? cnt[idx] : 0;
    }
#pragma unroll
    for (int m = 1; m < 64; m <<= 1) s += __shfl_xor(s, m, 64);
    if ((threadIdx.x & 63) == 0) sdata[threadIdx.x >> 6] = s;
    __syncthreads();
    if (threadIdx.x == 0)
        bsum[blockIdx.x] = sdata[0] + sdata[1] + sdata[2] + sdata[3];
}

// ---------------------------------------------------------------------------
// Scan pass 2: exclusive scan of chunk sums (nb <= 128)
// ---------------------------------------------------------------------------
__global__ __launch_bounds__(128)
void scan_bsum_kernel(int* __restrict__ bsum, int nb) {
    __shared__ int wtot[2];
    int t = threadIdx.x;
    int lane = t & 63;
    int orig = (t < nb) ? bsum[t] : 0;
    int v = orig;
#pragma unroll
    for (int m = 1; m < 64; m <<= 1) {
        int u = __shfl_up(v, m, 64);
        if (lane >= m) v += u;
    }
    if (lane == 63) wtot[t >> 6] = v;
    __syncthreads();
    if (t >= 64) v += wtot[0];
    if (t < nb) bsum[t] = v - orig;   // exclusive
}

// ---------------------------------------------------------------------------
// Scan pass 3: exclusive scan -> off[0..N], cursor copy into cnt[]
// ---------------------------------------------------------------------------
__global__ __launch_bounds__(256)
void scan_write_kernel(int* __restrict__ cnt, const int* __restrict__ bsum,
                       int* __restrict__ off, int N) {
    __shared__ int wsum[4];
    int t = threadIdx.x;
    int base = blockIdx.x * SCAN_CHUNK + t * 8;
    int vals[8];
    int local = 0;
#pragma unroll
    for (int k = 0; k < 8; ++k) {
        int idx = base + k;
        int c = (idx < N) ? cnt[idx] : 0;
        vals[k] = local;
        local += c;
    }
    int tsum = local;
    int lane = t & 63;
    int v = tsum;
#pragma unroll
    for (int m = 1; m < 64; m <<= 1) {
        int u = __shfl_up(v, m, 64);
        if (lane >= m) v += u;
    }
    if (lane == 63) wsum[t >> 6] = v;
    __syncthreads();
    int woff = 0;
    for (int i = 0; i < (t >> 6); ++i) woff += wsum[i];
    int texcl = (v - tsum) + woff + bsum[blockIdx.x];
#pragma unroll
    for (int k = 0; k < 8; ++k) {
        int idx = base + k;
        int o = texcl + vals[k];
        if (idx <= N) off[idx] = o;
    }
    __syncthreads();
#pragma unroll
    for (int k = 0; k < 8; ++k) {
        int idx = base + k;
        int o = texcl + vals[k];
        if (idx < N) cnt[idx] = o;
    }
}

// ---------------------------------------------------------------------------
// Reorder edges into CSR-by-target, packed (row, weight) int2
// ---------------------------------------------------------------------------
__global__ __launch_bounds__(256)
void reorder_kernel(const int* __restrict__ row, const int* __restrict__ col,
                    const float* __restrict__ w, int* __restrict__ cursor,
                    int2* __restrict__ edgeRW, int E) {
    int e = blockIdx.x * blockDim.x + threadIdx.x;
    if (e < E) {
        int c = col[e];
        int pos = atomicAdd(&cursor[c], 1);
        edgeRW[pos] = make_int2(row[e], __builtin_bit_cast(int, w[e]));
    }
}

// ---------------------------------------------------------------------------
// dinv from CSR: dinv[i] = rsqrt(1 + sum_j w_j)
// ---------------------------------------------------------------------------
__global__ __launch_bounds__(256)
void csr_dinv_kernel(const int* __restrict__ off, const int2* __restrict__ edgeRW,
                     float* __restrict__ dinv, int N) {
    int i = blockIdx.x * 256 + threadIdx.x;
    if (i >= N) return;
    int s = off[i], e = off[i + 1];
    float acc = 1.0f;
    for (int j = s; j < e; ++j)
        acc += __builtin_bit_cast(float, edgeRW[j].y);
    dinv[i] = rsqrtf(acc);
}

// ---------------------------------------------------------------------------
// PERSISTENT MFMA dual GEMM with counted-vmcnt depth-3 pipeline (T3+T4).
// 512 blocks x 512 threads; block owns a CONTIGUOUS range of 32-row tiles.
// LDS: 4 x 16 KB f32 buffers (+ dinv slice). Loop (per tile it):
//   s_waitcnt vmcnt(N)  -- counted: waits ONLY until this tile's 2 stage
//                          loads are done; stores & younger prefetches stay
//                          in flight (never vmcnt(0) in steady state)
//   s_barrier; sched_barrier fences (rule 18)
//   stage(it+3 -> buf (it+3)&3); compute buf it&3; 4 packed 8B stores
// FIFO accounting (loads=2/tile, stores=4/tile):
//   it0: [L0 L1 L2] -> vmcnt(4); it1: [L1 L2 L3 S0] -> 8; it2: -> 12
//   steady: after-L = S(4)+L(2)+S(4)+L(2)+S(4) = 16; tails: 14, 12
// W frags (64 VGPR) + biases hoisted; dinv slice pre-staged in LDS so the
// loop body has NO vmem ops besides the 2 stage loads + 4 stores.
//   hsb  = bf16(dinv*h) ; accb = bf16( leaky(f + bf) + bg + dinv*(dinv*h) )
// ---------------------------------------------------------------------------
__global__ __launch_bounds__(512, 4)
void gemm_mfma_kernel(const float* __restrict__ x_src, const float* __restrict__ x_tar,
                      int n_src, int n_total, int ntiles,
                      const unsigned short* __restrict__ WgT,
                      const unsigned short* __restrict__ WfT,
                      const float* __restrict__ bg, const float* __restrict__ bf,
                      const float* __restrict__ dinv,
                      unsigned short* __restrict__ hsb,
                      unsigned short* __restrict__ accb)
{
    __shared__ float Ash[4][32 * 128];   // 4 x 16 KB, 16B-chunk swizzled
    __shared__ float dinvS[448];         // dinv slice for this block's rows

    const int t    = threadIdx.x;
    const int lane = t & 63;
    const int wv   = t >> 6;          // 0..7
    const int h    = wv >> 2;         // row half (0..1): 16 rows
    const int q    = wv & 3;          // col quarter (0..3): 32 cols
    const int lr   = lane & 15;
    const int lk   = lane >> 4;

    // contiguous tile range for this block
    const int nb  = gridDim.x;
    const int K   = (ntiles + nb - 1) / nb;
    const int t0  = blockIdx.x * K;
    const int cnt = min(K, ntiles - t0);
    if (cnt <= 0) return;

    // ---- stage dinv slice into LDS (1 load; compiler waits before ds_write)
    if (t < cnt * 32) {
        int gi = t0 * 32 + t;
        if (gi >= n_total) gi = n_total - 1;
        dinvS[t] = dinv[gi];
    }
    asm volatile("s_waitcnt lgkmcnt(0)" ::: "memory");

    // ---- hoist W fragments + biases into registers (prologue vmem) ----
    short8v wg[4][2], wf[4][2];
#pragma unroll
    for (int ks = 0; ks < 4; ++ks)
#pragma unroll
        for (int nf = 0; nf < 2; ++nf) {
            int col = q * 32 + nf * 16 + lr;
            const size_t bo = (size_t)col * 128 + ks * 32 + lk * 8;
            wg[ks][nf] = *(const short8v*)(WgT + bo);
            wf[ks][nf] = *(const short8v*)(WfT + bo);
        }
    float4 bgv[2], bfv[2];
#pragma unroll
    for (int nf = 0; nf < 2; ++nf) {
        int c0 = q * 32 + nf * 16 + lk * 4;
        bgv[nf] = *(const float4*)(bg + c0);
        bfv[nf] = *(const float4*)(bf + c0);
    }

    // stage one 32-row tile: 1024 x 16B chunks / 512 threads = 2 DMA/thread
    auto stage = [&](int tl, int buf) {
#pragma unroll
        for (int s = 0; s < 2; ++s) {
            int id  = s * 512 + t;       // dest chunk id (linear)
            int row = id >> 5;           // 0..31
            int cs  = id & 31;
            int c   = cs ^ (row & 15);   // XOR-swizzled source chunk
            int rg  = tl * 32 + row;
            if (rg >= n_total) rg = n_total - 1;
            const float* xr = (rg < n_src) ? x_src + (size_t)rg * DIM
                                           : x_tar + (size_t)(rg - n_src) * DIM;
            gload_lds16(xr + c * 4, &Ash[buf][(size_t)(s * 512 + wv * 64) * 4]);
        }
    };

    // prologue: prefetch up to 3 tiles
    stage(t0, 0);
    if (1 < cnt) stage(t0 + 1, 1);
    if (2 < cnt) stage(t0 + 2, 2);

    const int xrow = h * 16 + lr;        // this lane's x row within tile
    const int xrs  = xrow & 15;

    for (int it = 0; it < cnt; ++it) {
        // counted wait: drain exactly through this tile's stage loads
        if (cnt >= 6) {
            if (it == 0)              asm volatile("s_waitcnt vmcnt(4)"  ::: "memory");
            else if (it == 1)         asm volatile("s_waitcnt vmcnt(8)"  ::: "memory");
            else if (it == 2)         asm volatile("s_waitcnt vmcnt(12)" ::: "memory");
            else if (it == cnt - 2)   asm volatile("s_waitcnt vmcnt(14)" ::: "memory");
            else if (it == cnt - 1)   asm volatile("s_waitcnt vmcnt(12)" ::: "memory");
            else                      asm volatile("s_waitcnt vmcnt(16)" ::: "memory");
        } else {
            asm volatile("s_waitcnt vmcnt(0)" ::: "memory");
        }
        __builtin_amdgcn_sched_barrier(0);
        __builtin_amdgcn_s_barrier();
        __builtin_amdgcn_sched_barrier(0);

        if (it + 3 < cnt) stage(t0 + it + 3, (it + 3) & 3);

        const int cur = it & 3;
        f32x4 accg[2], accf[2];
        accg[0] = (f32x4)0.0f; accg[1] = (f32x4)0.0f;
        accf[0] = (f32x4)0.0f; accf[1] = (f32x4)0.0f;

#pragma unroll
        for (int ks = 0; ks < 4; ++ks) {
            int c0 = ks * 8 + lk * 2;
            float4 q0 = *(const float4*)&Ash[cur][(size_t)(xrow * 32 + ( c0      ^ xrs)) * 4];
            float4 q1 = *(const float4*)&Ash[cur][(size_t)(xrow * 32 + ((c0 + 1) ^ xrs)) * 4];
            union { short8v v; unsigned u[4]; } cv;
            cv.u[0] = cvt_pk_bf16(q0.x, q0.y);
            cv.u[1] = cvt_pk_bf16(q0.z, q0.w);
            cv.u[2] = cvt_pk_bf16(q1.x, q1.y);
            cv.u[3] = cvt_pk_bf16(q1.z, q1.w);
#pragma unroll
            for (int nf = 0; nf < 2; ++nf) {
                accg[nf] = __builtin_amdgcn_mfma_f32_16x16x32_bf16(wg[ks][nf], cv.v, accg[nf], 0, 0, 0);
                accf[nf] = __builtin_amdgcn_mfma_f32_16x16x32_bf16(wf[ks][nf], cv.v, accf[nf], 0, 0, 0);
            }
        }

        // epilogue: lane owns (row r, cols c0..c0+3) per nf -> 8 B stores
        const int tile = t0 + it;
        int r = tile * 32 + xrow;
        const bool valid = (r < n_total);
        float dv = dinvS[it * 32 + xrow];
#pragma unroll
        for (int nf = 0; nf < 2; ++nf) {
            int c0 = q * 32 + nf * 16 + lk * 4;

            float hs0 = dv * accg[nf][0];
            float hs1 = dv * accg[nf][1];
            float hs2 = dv * accg[nf][2];
            float hs3 = dv * accg[nf][3];

            float o0 = leaky(accf[nf][0] + bfv[nf].x) + bgv[nf].x + dv * hs0;
            float o1 = leaky(accf[nf][1] + bfv[nf].y) + bgv[nf].y + dv * hs1;
            float o2 = leaky(accf[nf][2] + bfv[nf].z) + bgv[nf].z + dv * hs2;
            float o3 = leaky(accf[nf][3] + bfv[nf].w) + bgv[nf].w + dv * hs3;

            uint2 hp, op;
            hp.x = cvt_pk_bf16(hs0, hs1);
            hp.y = cvt_pk_bf16(hs2, hs3);
            op.x = cvt_pk_bf16(o0, o1);
            op.y = cvt_pk_bf16(o2, o3);

            if (valid) {
                *(uint2*)(hsb  + (size_t)r * DIM + c0) = hp;
                *(uint2*)(accb + (size_t)r * DIM + c0) = op;
            }
        }
    }
}

// ---------------------------------------------------------------------------
// Gather + fused layernorm + leaky_relu.
// 4 nodes per wave: 16 lanes x 8 dims each (16B uint4 gathers), pipelined.
//   out[i] = norm( accb[i] + dinv[i] * sum_{e->i} w_e * hsb[row_e] )
// ---------------------------------------------------------------------------
__global__ __launch_bounds__(256)
void gather_norm_kernel(const int* __restrict__ off, const int2* __restrict__ edgeRW,
                        const float* __restrict__ dinv,
                        const unsigned short* __restrict__ hsb,
                        const unsigned short* __restrict__ accb,
                        float* __restrict__ out, int n)
{
    const int wid  = threadIdx.x >> 6;
    const int lane = threadIdx.x & 63;
    const int sub  = lane >> 4;       // node within wave (0..3)
    const int sl   = lane & 15;       // lane within node, owns dims sl*8..+7
    int i = (blockIdx.x * 4 + wid) * 4 + sub;
    if (i >= n) i = n - 1;

    const int start = off[i];
    const int degc  = off[i + 1] - start;

    int md = degc;
    md = max(md, __shfl_xor(md, 16, 64));
    md = max(md, __shfl_xor(md, 32, 64));

    float s[8];
#pragma unroll
    for (int k = 0; k < 8; ++k) s[k] = 0.0f;

    const unsigned short* gbase = hsb + (size_t)sl * 8;

    int   r0 = 0, r1 = 0;
    float w0 = 0.0f, w1 = 0.0f;
    if (0 < degc) { int2 m = edgeRW[start];     r0 = m.x; w0 = __builtin_bit_cast(float, m.y); }
    if (1 < degc) { int2 m = edgeRW[start + 1]; r1 = m.x; w1 = __builtin_bit_cast(float, m.y); }
    uint4 p0 = *(const uint4*)(gbase + (size_t)r0 * DIM);

    for (int t = 0; t < md; ++t) {
        uint4 p1 = p0;
        if (t + 1 < md)
            p1 = *(const uint4*)(gbase + (size_t)r1 * DIM);
        int r2 = 0; float w2 = 0.0f;
        if (t + 2 < md) {
            if (t + 2 < degc) {
                int2 m = edgeRW[start + t + 2];
                r2 = m.x; w2 = __builtin_bit_cast(float, m.y);
            }
        }
        s[0] += w0 * bf2f_lo(p0.x); s[1] += w0 * bf2f_hi(p0.x);
        s[2] += w0 * bf2f_lo(p0.y); s[3] += w0 * bf2f_hi(p0.y);
        s[4] += w0 * bf2f_lo(p0.z); s[5] += w0 * bf2f_hi(p0.z);
        s[6] += w0 * bf2f_lo(p0.w); s[7] += w0 * bf2f_hi(p0.w);
        p0 = p1;
        r0 = r1; w0 = w1;
        r1 = r2; w1 = w2;
    }

    const float dv = dinv[i];
    uint4 av = *(const uint4*)(accb + (size_t)i * DIM + sl * 8);
    float v[8];
    v[0] = bf2f_lo(av.x) + dv * s[0]; v[1] = bf2f_hi(av.x) + dv * s[1];
    v[2] = bf2f_lo(av.y) + dv * s[2]; v[3] = bf2f_hi(av.y) + dv * s[3];
    v[4] = bf2f_lo(av.z) + dv * s[4]; v[5] = bf2f_hi(av.z) + dv * s[5];
    v[6] = bf2f_lo(av.w) + dv * s[6]; v[7] = bf2f_hi(av.w) + dv * s[7];

    float sum = 0.0f;
#pragma unroll
    for (int k = 0; k < 8; ++k) sum += v[k];
#pragma unroll
    for (int m = 1; m < 16; m <<= 1) sum += __shfl_xor(sum, m, 64);
    const float mean = sum * (1.0f / 128.0f);

    float sq = 0.0f;
#pragma unroll
    for (int k = 0; k < 8; ++k) {
        v[k] -= mean;
        sq += v[k] * v[k];
    }
#pragma unroll
    for (int m = 1; m < 16; m <<= 1) sq += __shfl_xor(sq, m, 64);
    const float rstd = rsqrtf(sq * (1.0f / 128.0f) + 1e-6f);

    float4 o1, o2;
    o1.x = leaky(v[0] * rstd); o1.y = leaky(v[1] * rstd);
    o1.z = leaky(v[2] * rstd); o1.w = leaky(v[3] * rstd);
    o2.x = leaky(v[4] * rstd); o2.y = leaky(v[5] * rstd);
    o2.z = leaky(v[6] * rstd); o2.w = leaky(v[7] * rstd);
    float* op = out + (size_t)i * DIM + sl * 8;
    *(float4*)op       = o1;
    *(float4*)(op + 4) = o2;
}

// ---------------------------------------------------------------------------
extern "C" void kernel_launch(void* const* d_in, const int* in_sizes, int n_in,
                              void* d_out, int out_size, void* d_ws, size_t ws_size,
                              hipStream_t stream)
{
    const float* x_src = (const float*)d_in[0];
    const float* x_tar = (const float*)d_in[1];
    const int*   ei    = (const int*)d_in[2];
    const float* ew    = (const float*)d_in[3];
    const float* Wg    = (const float*)d_in[4];
    const float* bg    = (const float*)d_in[5];
    const float* Wf    = (const float*)d_in[6];
    const float* bf    = (const float*)d_in[7];

    const int n_src = in_sizes[0] / DIM;
    const int n_tar = in_sizes[1] / DIM;
    const int N     = n_src + n_tar;
    const int E     = in_sizes[3];

    const int* rowp = ei;       // edge_index[0] = message source
    const int* colp = ei + E;   // edge_index[1] = message target

    // ---- workspace layout ----
    char* p = (char*)d_ws;
    float* dinv = (float*)p;  p += (size_t)N * 4;
    int*   cnt  = (int*)p;    p += (size_t)N * 4;
    int*   off  = (int*)p;    p += (size_t)(N + 1) * 4;
    int*   bsum = (int*)p;    p += 160 * 4;
    p = (char*)(((uintptr_t)p + 15) & ~(uintptr_t)15);
    int2*  edgeRW = (int2*)p; p += (size_t)E * 8;
    unsigned short* hsb  = (unsigned short*)p; p += (size_t)N * DIM * 2;
    unsigned short* accb = (unsigned short*)p; p += (size_t)N * DIM * 2;
    unsigned short* WgT  = (unsigned short*)p; p += 128 * 128 * 2;
    unsigned short* WfT  = (unsigned short*)p;

    const int NB = (N + 1 + SCAN_CHUNK - 1) / SCAN_CHUNK;

    init_kernel<<<(N + 255) / 256, 256, 0, stream>>>(Wg, Wf, WgT, WfT, cnt, N);

    hist_kernel<<<(E + 255) / 256, 256, 0, stream>>>(colp, cnt, E);

    scan_block_sums<<<NB, 256, 0, stream>>>(cnt, bsum, N);
    scan_bsum_kernel<<<1, 128, 0, stream>>>(bsum, NB);
    scan_write_kernel<<<NB, 256, 0, stream>>>(cnt, bsum, off, N);

    reorder_kernel<<<(E + 255) / 256, 256, 0, stream>>>(rowp, colp, ew, cnt,
                                                        edgeRW, E);

    csr_dinv_kernel<<<(N + 255) / 256, 256, 0, stream>>>(off, edgeRW, dinv, N);

    const int ntiles = (N + 31) / 32;
    gemm_mfma_kernel<<<512, 512, 0, stream>>>(
        x_src, x_tar, n_src, N, ntiles, WgT, WfT, bg, bf, dinv, hsb, accb);

    gather_norm_kernel<<<(N + 15) / 16, 256, 0, stream>>>(
        off, edgeRW, dinv, hsb, accb, (float*)d_out, N);
}

// Round 11
// 194.370 us; speedup vs baseline: 1.1639x; 1.0577x over previous
//
#include <hip/hip_runtime.h>
#include <hip/hip_bf16.h>
#include <cstddef>
#include <cstdint>

#define DIM 128
#define SCAN_CHUNK 2048   // 256 threads x 8 elems

typedef __attribute__((ext_vector_type(8))) short short8v;  // 8 bf16 (4 VGPR)
typedef __attribute__((ext_vector_type(4))) float f32x4;    // MFMA acc

__device__ __forceinline__ float leaky(float v) {
    return v > 0.0f ? v : 0.01f * v;
}

__device__ __forceinline__ unsigned short f2bf(float f) {
    unsigned u = __builtin_bit_cast(unsigned, f);
    u += 0x7FFF + ((u >> 16) & 1);      // round-to-nearest-even
    return (unsigned short)(u >> 16);
}

// pack two f32 -> one u32 of 2 bf16 (lo = a, hi = b), single HW instr
__device__ __forceinline__ unsigned cvt_pk_bf16(float a, float b) {
    unsigned r;
    asm("v_cvt_pk_bf16_f32 %0, %1, %2" : "=v"(r) : "v"(a), "v"(b));
    return r;
}

__device__ __forceinline__ float bf2f_hi(unsigned p) {
    return __builtin_bit_cast(float, p & 0xFFFF0000u);
}
__device__ __forceinline__ float bf2f_lo(unsigned p) {
    return __builtin_bit_cast(float, p << 16);
}

// async global->LDS, 16 B per lane; LDS dest = wave-uniform base + lane*16
__device__ __forceinline__ void gload_lds16(const float* g, float* lds) {
    __builtin_amdgcn_global_load_lds(
        (const __attribute__((address_space(1))) unsigned int*)g,
        (__attribute__((address_space(3))) unsigned int*)lds, 16, 0, 0);
}

// ---------------------------------------------------------------------------
// init: zero cnt[]  +  W transpose/convert
// ---------------------------------------------------------------------------
__global__ __launch_bounds__(256)
void init_kernel(const float* __restrict__ Wg, const float* __restrict__ Wf,
                 unsigned short* __restrict__ WgT, unsigned short* __restrict__ WfT,
                 int* __restrict__ cnt, int N) {
    int t = blockIdx.x * 256 + threadIdx.x;
    if (t < N) cnt[t] = 0;
    if (t < 128 * 128) {
        int col = t >> 7, k = t & 127;
        WgT[col * 128 + k] = f2bf(Wg[k * 128 + col]);
        WfT[col * 128 + k] = f2bf(Wf[k * 128 + col]);
    }
}

// ---------------------------------------------------------------------------
// histogram of in-degree counts
// ---------------------------------------------------------------------------
__global__ __launch_bounds__(256)
void hist_kernel(const int* __restrict__ col, int* __restrict__ cnt, int E) {
    int e = blockIdx.x * blockDim.x + threadIdx.x;
    if (e < E) atomicAdd(&cnt[col[e]], 1);
}

// ---------------------------------------------------------------------------
// Scan pass 1: per-chunk sums of cnt
// ---------------------------------------------------------------------------
__global__ __launch_bounds__(256)
void scan_block_sums(const int* __restrict__ cnt, int* __restrict__ bsum, int N) {
    __shared__ int sdata[4];
    int base = blockIdx.x * SCAN_CHUNK;
    int s = 0;
    for (int k = threadIdx.x; k < SCAN_CHUNK; k += 256) {
        int idx = base + k;
        s += (idx < N) ? cnt[idx] : 0;
    }
#pragma unroll
    for (int m = 1; m < 64; m <<= 1) s += __shfl_xor(s, m, 64);
    if ((threadIdx.x & 63) == 0) sdata[threadIdx.x >> 6] = s;
    __syncthreads();
    if (threadIdx.x == 0)
        bsum[blockIdx.x] = sdata[0] + sdata[1] + sdata[2] + sdata[3];
}

// ---------------------------------------------------------------------------
// Scan pass 2: exclusive scan of chunk sums (nb <= 128)
// ---------------------------------------------------------------------------
__global__ __launch_bounds__(128)
void scan_bsum_kernel(int* __restrict__ bsum, int nb) {
    __shared__ int wtot[2];
    int t = threadIdx.x;
    int lane = t & 63;
    int orig = (t < nb) ? bsum[t] : 0;
    int v = orig;
#pragma unroll
    for (int m = 1; m < 64; m <<= 1) {
        int u = __shfl_up(v, m, 64);
        if (lane >= m) v += u;
    }
    if (lane == 63) wtot[t >> 6] = v;
    __syncthreads();
    if (t >= 64) v += wtot[0];
    if (t < nb) bsum[t] = v - orig;   // exclusive
}

// ---------------------------------------------------------------------------
// Scan pass 3: exclusive scan -> off[0..N], cursor copy into cnt[]
// ---------------------------------------------------------------------------
__global__ __launch_bounds__(256)
void scan_write_kernel(int* __restrict__ cnt, const int* __restrict__ bsum,
                       int* __restrict__ off, int N) {
    __shared__ int wsum[4];
    int t = threadIdx.x;
    int base = blockIdx.x * SCAN_CHUNK + t * 8;
    int vals[8];
    int local = 0;
#pragma unroll
    for (int k = 0; k < 8; ++k) {
        int idx = base + k;
        int c = (idx < N) ? cnt[idx] : 0;
        vals[k] = local;
        local += c;
    }
    int tsum = local;
    int lane = t & 63;
    int v = tsum;
#pragma unroll
    for (int m = 1; m < 64; m <<= 1) {
        int u = __shfl_up(v, m, 64);
        if (lane >= m) v += u;
    }
    if (lane == 63) wsum[t >> 6] = v;
    __syncthreads();
    int woff = 0;
    for (int i = 0; i < (t >> 6); ++i) woff += wsum[i];
    int texcl = (v - tsum) + woff + bsum[blockIdx.x];
#pragma unroll
    for (int k = 0; k < 8; ++k) {
        int idx = base + k;
        int o = texcl + vals[k];
        if (idx <= N) off[idx] = o;
    }
    __syncthreads();
#pragma unroll
    for (int k = 0; k < 8; ++k) {
        int idx = base + k;
        int o = texcl + vals[k];
        if (idx < N) cnt[idx] = o;
    }
}

// ---------------------------------------------------------------------------
// Reorder edges into CSR-by-target, packed (row, weight) int2
// ---------------------------------------------------------------------------
__global__ __launch_bounds__(256)
void reorder_kernel(const int* __restrict__ row, const int* __restrict__ col,
                    const float* __restrict__ w, int* __restrict__ cursor,
                    int2* __restrict__ edgeRW, int E) {
    int e = blockIdx.x * blockDim.x + threadIdx.x;
    if (e < E) {
        int c = col[e];
        int pos = atomicAdd(&cursor[c], 1);
        edgeRW[pos] = make_int2(row[e], __builtin_bit_cast(int, w[e]));
    }
}

// ---------------------------------------------------------------------------
// dinv from CSR: dinv[i] = rsqrt(1 + sum_j w_j)
// ---------------------------------------------------------------------------
__global__ __launch_bounds__(256)
void csr_dinv_kernel(const int* __restrict__ off, const int2* __restrict__ edgeRW,
                     float* __restrict__ dinv, int N) {
    int i = blockIdx.x * 256 + threadIdx.x;
    if (i >= N) return;
    int s = off[i], e = off[i + 1];
    float acc = 1.0f;
    for (int j = s; j < e; ++j)
        acc += __builtin_bit_cast(float, edgeRW[j].y);
    dinv[i] = rsqrtf(acc);
}

// ---------------------------------------------------------------------------
// PERSISTENT MFMA dual GEMM, counted-vmcnt depth-3 pipeline, CONTIGUOUS
// per-lane output columns.
// W-column PERMUTATION in the A-fragment (col = q*32 + (lr>>2)*8 + nf*4 +
// (lr&3)) makes MFMA nf=0 produce cols lk*8+0..3 and nf=1 cols lk*8+4..7
// for each lane -> one 16 B dwordx4 store per buffer per tile; a wave's
// store covers 64 B full cachelines per row (was 64 scattered 8 B pieces).
// vmcnt FIFO (loads=2/tile, stores=2/tile):
//   it0:4  it1:6  it2:8  steady:10  it=cnt-2:8  it=cnt-1:6   (never 0)
//   hsb  = bf16(dinv*h) ; accb = bf16( leaky(f + bf) + bg + dinv*(dinv*h) )
// ---------------------------------------------------------------------------
__global__ __launch_bounds__(512, 4)
void gemm_mfma_kernel(const float* __restrict__ x_src, const float* __restrict__ x_tar,
                      int n_src, int n_total, int ntiles,
                      const unsigned short* __restrict__ WgT,
                      const unsigned short* __restrict__ WfT,
                      const float* __restrict__ bg, const float* __restrict__ bf,
                      const float* __restrict__ dinv,
                      unsigned short* __restrict__ hsb,
                      unsigned short* __restrict__ accb)
{
    __shared__ float Ash[4][32 * 128];   // 4 x 16 KB, 16B-chunk swizzled
    __shared__ float dinvS[448];         // dinv slice for this block's rows

    const int t    = threadIdx.x;
    const int lane = t & 63;
    const int wv   = t >> 6;          // 0..7
    const int h    = wv >> 2;         // row half (0..1): 16 rows
    const int q    = wv & 3;          // col quarter (0..3): 32 cols
    const int lr   = lane & 15;
    const int lk   = lane >> 4;

    // contiguous tile range for this block
    const int nb  = gridDim.x;
    const int K   = (ntiles + nb - 1) / nb;
    const int t0  = blockIdx.x * K;
    const int cnt = min(K, ntiles - t0);
    if (cnt <= 0) return;

    // ---- stage dinv slice into LDS ----
    if (t < cnt * 32) {
        int gi = t0 * 32 + t;
        if (gi >= n_total) gi = n_total - 1;
        dinvS[t] = dinv[gi];
    }
    asm volatile("s_waitcnt lgkmcnt(0)" ::: "memory");

    // ---- hoist W fragments + biases, PERMUTED columns ----
    // A-frag row m holds W col q*32 + (m>>2)*8 + nf*4 + (m&3)
    // -> lane's D regs (rows lk*4+reg) = cols q*32 + lk*8 + nf*4 + reg
    short8v wg[4][2], wf[4][2];
#pragma unroll
    for (int ks = 0; ks < 4; ++ks)
#pragma unroll
        for (int nf = 0; nf < 2; ++nf) {
            int col = q * 32 + ((lr >> 2) << 3) + nf * 4 + (lr & 3);
            const size_t bo = (size_t)col * 128 + ks * 32 + lk * 8;
            wg[ks][nf] = *(const short8v*)(WgT + bo);
            wf[ks][nf] = *(const short8v*)(WfT + bo);
        }
    // biases for this lane's 8 consecutive cols (cb .. cb+7)
    const int cb = q * 32 + lk * 8;
    float4 bgv[2], bfv[2];
#pragma unroll
    for (int nf = 0; nf < 2; ++nf) {
        bgv[nf] = *(const float4*)(bg + cb + nf * 4);
        bfv[nf] = *(const float4*)(bf + cb + nf * 4);
    }

    // stage one 32-row tile: 1024 x 16B chunks / 512 threads = 2 DMA/thread
    auto stage = [&](int tl, int buf) {
#pragma unroll
        for (int s = 0; s < 2; ++s) {
            int id  = s * 512 + t;       // dest chunk id (linear)
            int row = id >> 5;           // 0..31
            int cs  = id & 31;
            int c   = cs ^ (row & 15);   // XOR-swizzled source chunk
            int rg  = tl * 32 + row;
            if (rg >= n_total) rg = n_total - 1;
            const float* xr = (rg < n_src) ? x_src + (size_t)rg * DIM
                                           : x_tar + (size_t)(rg - n_src) * DIM;
            gload_lds16(xr + c * 4, &Ash[buf][(size_t)(s * 512 + wv * 64) * 4]);
        }
    };

    // prologue: prefetch up to 3 tiles
    stage(t0, 0);
    if (1 < cnt) stage(t0 + 1, 1);
    if (2 < cnt) stage(t0 + 2, 2);

    const int xrow = h * 16 + lr;        // this lane's x row within tile
    const int xrs  = xrow & 15;

    for (int it = 0; it < cnt; ++it) {
        // counted wait: drain exactly through this tile's 2 stage loads
        if (cnt >= 6) {
            if (it == 0)              asm volatile("s_waitcnt vmcnt(4)"  ::: "memory");
            else if (it == 1)         asm volatile("s_waitcnt vmcnt(6)"  ::: "memory");
            else if (it == 2)         asm volatile("s_waitcnt vmcnt(8)"  ::: "memory");
            else if (it == cnt - 2)   asm volatile("s_waitcnt vmcnt(8)"  ::: "memory");
            else if (it == cnt - 1)   asm volatile("s_waitcnt vmcnt(6)"  ::: "memory");
            else                      asm volatile("s_waitcnt vmcnt(10)" ::: "memory");
        } else {
            asm volatile("s_waitcnt vmcnt(0)" ::: "memory");
        }
        __builtin_amdgcn_sched_barrier(0);
        __builtin_amdgcn_s_barrier();
        __builtin_amdgcn_sched_barrier(0);

        if (it + 3 < cnt) stage(t0 + it + 3, (it + 3) & 3);

        const int cur = it & 3;
        f32x4 accg[2], accf[2];
        accg[0] = (f32x4)0.0f; accg[1] = (f32x4)0.0f;
        accf[0] = (f32x4)0.0f; accf[1] = (f32x4)0.0f;

#pragma unroll
        for (int ks = 0; ks < 4; ++ks) {
            int c0 = ks * 8 + lk * 2;
            float4 q0 = *(const float4*)&Ash[cur][(size_t)(xrow * 32 + ( c0      ^ xrs)) * 4];
            float4 q1 = *(const float4*)&Ash[cur][(size_t)(xrow * 32 + ((c0 + 1) ^ xrs)) * 4];
            union { short8v v; unsigned u[4]; } cv;
            cv.u[0] = cvt_pk_bf16(q0.x, q0.y);
            cv.u[1] = cvt_pk_bf16(q0.z, q0.w);
            cv.u[2] = cvt_pk_bf16(q1.x, q1.y);
            cv.u[3] = cvt_pk_bf16(q1.z, q1.w);
#pragma unroll
            for (int nf = 0; nf < 2; ++nf) {
                accg[nf] = __builtin_amdgcn_mfma_f32_16x16x32_bf16(wg[ks][nf], cv.v, accg[nf], 0, 0, 0);
                accf[nf] = __builtin_amdgcn_mfma_f32_16x16x32_bf16(wf[ks][nf], cv.v, accf[nf], 0, 0, 0);
            }
        }

        // epilogue: lane owns (row r, cols cb..cb+7) -> ONE 16 B store/buffer
        const int tile = t0 + it;
        int r = tile * 32 + xrow;
        const bool valid = (r < n_total);
        float dv = dinvS[it * 32 + xrow];

        float hs[8], oo[8];
#pragma unroll
        for (int nf = 0; nf < 2; ++nf)
#pragma unroll
            for (int e = 0; e < 4; ++e) {
                int k = nf * 4 + e;
                hs[k] = dv * accg[nf][e];
                float f = accf[nf][e] + ((const float*)&bfv[nf])[e];
                oo[k] = leaky(f) + ((const float*)&bgv[nf])[e] + dv * hs[k];
            }

        uint4 hp, op;
        hp.x = cvt_pk_bf16(hs[0], hs[1]); hp.y = cvt_pk_bf16(hs[2], hs[3]);
        hp.z = cvt_pk_bf16(hs[4], hs[5]); hp.w = cvt_pk_bf16(hs[6], hs[7]);
        op.x = cvt_pk_bf16(oo[0], oo[1]); op.y = cvt_pk_bf16(oo[2], oo[3]);
        op.z = cvt_pk_bf16(oo[4], oo[5]); op.w = cvt_pk_bf16(oo[6], oo[7]);

        if (valid) {
            *(uint4*)(hsb  + (size_t)r * DIM + cb) = hp;
            *(uint4*)(accb + (size_t)r * DIM + cb) = op;
        }
    }
}

// ---------------------------------------------------------------------------
// Gather + fused layernorm + leaky_relu.
// 4 nodes per wave: 16 lanes x 8 dims each (16B uint4 gathers), pipelined.
//   out[i] = norm( accb[i] + dinv[i] * sum_{e->i} w_e * hsb[row_e] )
// ---------------------------------------------------------------------------
__global__ __launch_bounds__(256)
void gather_norm_kernel(const int* __restrict__ off, const int2* __restrict__ edgeRW,
                        const float* __restrict__ dinv,
                        const unsigned short* __restrict__ hsb,
                        const unsigned short* __restrict__ accb,
                        float* __restrict__ out, int n)
{
    const int wid  = threadIdx.x >> 6;
    const int lane = threadIdx.x & 63;
    const int sub  = lane >> 4;       // node within wave (0..3)
    const int sl   = lane & 15;       // lane within node, owns dims sl*8..+7
    int i = (blockIdx.x * 4 + wid) * 4 + sub;
    if (i >= n) i = n - 1;

    const int start = off[i];
    const int degc  = off[i + 1] - start;

    int md = degc;
    md = max(md, __shfl_xor(md, 16, 64));
    md = max(md, __shfl_xor(md, 32, 64));

    float s[8];
#pragma unroll
    for (int k = 0; k < 8; ++k) s[k] = 0.0f;

    const unsigned short* gbase = hsb + (size_t)sl * 8;

    int   r0 = 0, r1 = 0;
    float w0 = 0.0f, w1 = 0.0f;
    if (0 < degc) { int2 m = edgeRW[start];     r0 = m.x; w0 = __builtin_bit_cast(float, m.y); }
    if (1 < degc) { int2 m = edgeRW[start + 1]; r1 = m.x; w1 = __builtin_bit_cast(float, m.y); }
    uint4 p0 = *(const uint4*)(gbase + (size_t)r0 * DIM);

    for (int t = 0; t < md; ++t) {
        uint4 p1 = p0;
        if (t + 1 < md)
            p1 = *(const uint4*)(gbase + (size_t)r1 * DIM);
        int r2 = 0; float w2 = 0.0f;
        if (t + 2 < md) {
            if (t + 2 < degc) {
                int2 m = edgeRW[start + t + 2];
                r2 = m.x; w2 = __builtin_bit_cast(float, m.y);
            }
        }
        s[0] += w0 * bf2f_lo(p0.x); s[1] += w0 * bf2f_hi(p0.x);
        s[2] += w0 * bf2f_lo(p0.y); s[3] += w0 * bf2f_hi(p0.y);
        s[4] += w0 * bf2f_lo(p0.z); s[5] += w0 * bf2f_hi(p0.z);
        s[6] += w0 * bf2f_lo(p0.w); s[7] += w0 * bf2f_hi(p0.w);
        p0 = p1;
        r0 = r1; w0 = w1;
        r1 = r2; w1 = w2;
    }

    const float dv = dinv[i];
    uint4 av = *(const uint4*)(accb + (size_t)i * DIM + sl * 8);
    float v[8];
    v[0] = bf2f_lo(av.x) + dv * s[0]; v[1] = bf2f_hi(av.x) + dv * s[1];
    v[2] = bf2f_lo(av.y) + dv * s[2]; v[3] = bf2f_hi(av.y) + dv * s[3];
    v[4] = bf2f_lo(av.z) + dv * s[4]; v[5] = bf2f_hi(av.z) + dv * s[5];
    v[6] = bf2f_lo(av.w) + dv * s[6]; v[7] = bf2f_hi(av.w) + dv * s[7];

    float sum = 0.0f;
#pragma unroll
    for (int k = 0; k < 8; ++k) sum += v[k];
#pragma unroll
    for (int m = 1; m < 16; m <<= 1) sum += __shfl_xor(sum, m, 64);
    const float mean = sum * (1.0f / 128.0f);

    float sq = 0.0f;
#pragma unroll
    for (int k = 0; k < 8; ++k) {
        v[k] -= mean;
        sq += v[k] * v[k];
    }
#pragma unroll
    for (int m = 1; m < 16; m <<= 1) sq += __shfl_xor(sq, m, 64);
    const float rstd = rsqrtf(sq * (1.0f / 128.0f) + 1e-6f);

    float4 o1, o2;
    o1.x = leaky(v[0] * rstd); o1.y = leaky(v[1] * rstd);
    o1.z = leaky(v[2] * rstd); o1.w = leaky(v[3] * rstd);
    o2.x = leaky(v[4] * rstd); o2.y = leaky(v[5] * rstd);
    o2.z = leaky(v[6] * rstd); o2.w = leaky(v[7] * rstd);
    float* op = out + (size_t)i * DIM + sl * 8;
    *(float4*)op       = o1;
    *(float4*)(op + 4) = o2;
}

// ---------------------------------------------------------------------------
extern "C" void kernel_launch(void* const* d_in, const int* in_sizes, int n_in,
                              void* d_out, int out_size, void* d_ws, size_t ws_size,
                              hipStream_t stream)
{
    const float* x_src = (const float*)d_in[0];
    const float* x_tar = (const float*)d_in[1];
    const int*   ei    = (const int*)d_in[2];
    const float* ew    = (const float*)d_in[3];
    const float* Wg    = (const float*)d_in[4];
    const float* bg    = (const float*)d_in[5];
    const float* Wf    = (const float*)d_in[6];
    const float* bf    = (const float*)d_in[7];

    const int n_src = in_sizes[0] / DIM;
    const int n_tar = in_sizes[1] / DIM;
    const int N     = n_src + n_tar;
    const int E     = in_sizes[3];

    const int* rowp = ei;       // edge_index[0] = message source
    const int* colp = ei + E;   // edge_index[1] = message target

    // ---- workspace layout ----
    char* p = (char*)d_ws;
    float* dinv = (float*)p;  p += (size_t)N * 4;
    int*   cnt  = (int*)p;    p += (size_t)N * 4;
    int*   off  = (int*)p;    p += (size_t)(N + 1) * 4;
    int*   bsum = (int*)p;    p += 160 * 4;
    p = (char*)(((uintptr_t)p + 15) & ~(uintptr_t)15);
    int2*  edgeRW = (int2*)p; p += (size_t)E * 8;
    unsigned short* hsb  = (unsigned short*)p; p += (size_t)N * DIM * 2;
    unsigned short* accb = (unsigned short*)p; p += (size_t)N * DIM * 2;
    unsigned short* WgT  = (unsigned short*)p; p += 128 * 128 * 2;
    unsigned short* WfT  = (unsigned short*)p;

    const int NB = (N + 1 + SCAN_CHUNK - 1) / SCAN_CHUNK;

    init_kernel<<<(N + 255) / 256, 256, 0, stream>>>(Wg, Wf, WgT, WfT, cnt, N);

    hist_kernel<<<(E + 255) / 256, 256, 0, stream>>>(colp, cnt, E);

    scan_block_sums<<<NB, 256, 0, stream>>>(cnt, bsum, N);
    scan_bsum_kernel<<<1, 128, 0, stream>>>(bsum, NB);
    scan_write_kernel<<<NB, 256, 0, stream>>>(cnt, bsum, off, N);

    reorder_kernel<<<(E + 255) / 256, 256, 0, stream>>>(rowp, colp, ew, cnt,
                                                        edgeRW, E);

    csr_dinv_kernel<<<(N + 255) / 256, 256, 0, stream>>>(off, edgeRW, dinv, N);

    const int ntiles = (N + 31) / 32;
    gemm_mfma_kernel<<<512, 512, 0, stream>>>(
        x_src, x_tar, n_src, N, ntiles, WgT, WfT, bg, bf, dinv, hsb, accb);

    gather_norm_kernel<<<(N + 15) / 16, 256, 0, stream>>>(
        off, edgeRW, dinv, hsb, accb, (float*)d_out, N);
}